// Round 2
// baseline (145.390 us; speedup 1.0000x reference)
//
#include <hip/hip_runtime.h>
#include <math.h>

// Problem constants (from reference setup_inputs)
#define TEMP 0.07f
constexpr int B = 2048;
constexpr int V = 2;
constexpr int D = 256;
constexpr int C = 1000;
constexpr int N = V * B;   // 4096
constexpr int BK = 32;     // K-tile width (elements)
constexpr int KB = D / BK; // 8 K-blocks

typedef __attribute__((ext_vector_type(8))) short bf16x8;   // 8 bf16 (4 VGPRs)
typedef __attribute__((ext_vector_type(4))) float floatx4;  // MFMA accumulator

__device__ __forceinline__ short f2bf(float x) {
  union { float f; unsigned u; } v; v.f = x;
  unsigned r = v.u + 0x7FFF + ((v.u >> 16) & 1);  // round-to-nearest-even
  return (short)(r >> 16);
}

// ---------------------------------------------------------------------------
// prep kernel: block-range fused
//   [0, 1024)    : L2-normalize rows -> cf in K-tiled layout [kb][N][32] bf16
//   [1024, 1536) : per-sample focal modulation (softmax over preds)
//   1536         : zero Z, P, counter
//   1537         : label histogram (for positive counts)
// ---------------------------------------------------------------------------
__global__ __launch_bounds__(256) void prep_kernel(
    const float* __restrict__ feat, const float* __restrict__ preds,
    const int* __restrict__ labels, short* __restrict__ cf,
    float* __restrict__ modv, int* __restrict__ hist,
    float* __restrict__ zp_zero, unsigned* __restrict__ counter) {
  const int bid = blockIdx.x;
  const int tid = threadIdx.x;
  if (bid < 1024) {
    // ---- normalize: one wave per row i of cf ----
    int i = (bid << 2) | (tid >> 6);   // [0, 4096)
    int lane = tid & 63;
    int v = i >> 11;
    int b = i & (B - 1);
    const float* src = feat + (size_t)(b * V + v) * D;
    float4 x = ((const float4*)src)[lane];
    float ss = x.x * x.x + x.y * x.y + x.z * x.z + x.w * x.w;
    #pragma unroll
    for (int m = 32; m; m >>= 1) ss += __shfl_xor(ss, m);
    float inv = rsqrtf(ss);
    short4 o;
    o.x = f2bf(x.x * inv); o.y = f2bf(x.y * inv);
    o.z = f2bf(x.z * inv); o.w = f2bf(x.w * inv);
    // K-tiled layout: elem offset = (kb*N + i)*BK + k_in_block
    // lane holds k = 4*lane .. 4*lane+3  ->  kb = lane>>3, k_in = (lane&7)*4
    size_t off = ((size_t)(lane >> 3) * N + i) * BK + (lane & 7) * 4;
    *(short4*)(cf + off) = o;
  } else if (bid < 1536) {
    // ---- focal modulation: one wave per sample b ----
    int b = ((bid - 1024) << 2) | (tid >> 6);  // [0, 2048)
    int lane = tid & 63;
    const float* p = preds + (size_t)b * C;
    float m = -1e30f;
    for (int j = lane; j < C; j += 64) m = fmaxf(m, p[j]);
    #pragma unroll
    for (int mk = 32; mk; mk >>= 1) m = fmaxf(m, __shfl_xor(m, mk));
    float s = 0.f;
    for (int j = lane; j < C; j += 64) s += __expf(p[j] - m);
    #pragma unroll
    for (int mk = 32; mk; mk >>= 1) s += __shfl_xor(s, mk);
    int lab = labels[b];
    float nll = p[lab] - (m + logf(s));  // log p_t
    float pt = __expf(nll);
    float md = 1.f - pt;
    md = md * md;  // gamma = 2
    if (lane == 0) modv[b] = md;
  } else if (bid == 1536) {
    // ---- zero Z (16KB) + P (16KB) + counter ----
    float4* z4 = (float4*)zp_zero;  // 2048 float4
    float4 zz; zz.x = zz.y = zz.z = zz.w = 0.f;
    for (int t = tid; t < 2048; t += 256) z4[t] = zz;
    if (tid == 0) *counter = 0u;
  } else {
    // ---- label histogram ----
    __shared__ int h[C];
    for (int t = tid; t < C; t += 256) h[t] = 0;
    __syncthreads();
    for (int t = tid; t < B; t += 256) atomicAdd(&h[labels[t]], 1);
    __syncthreads();
    for (int t = tid; t < C; t += 256) hist[t] = h[t];
  }
}

// ---------------------------------------------------------------------------
// gram kernel: S = cf*cf^T / T with fused epilogue + fused finalize.
// Per row i: Z[i] = sum_{j!=i} exp(s_ij - 1/T)   (1/T is a valid LSE shift
//            since all rows are unit vectors => s_ij <= 1/T)
//            P[i] = sum_{j!=i, label match} s_ij
// Block = 128x128 tile, 4 waves 2x2, each wave 64x64 via 4x4 MFMA 16x16x32.
// Fragments load DIRECTLY from global: K-tiled cf makes each bf16x8 wave-load
// one contiguous 1KB span (fully coalesced, L2-resident). No LDS, no barriers
// in the K-loop. Last block to finish runs the 4096-row finalize reduction.
// ---------------------------------------------------------------------------
__global__ __launch_bounds__(256) void gram_kernel(
    const short* __restrict__ cf, const int* __restrict__ labels,
    const float* __restrict__ modv, const int* __restrict__ hist,
    float* __restrict__ Z, float* __restrict__ P,
    unsigned* __restrict__ counter, float* __restrict__ out) {
  const int lane = threadIdx.x & 63;
  const int wave = threadIdx.x >> 6;
  const int row0 = blockIdx.y * 128 + (wave >> 1) * 64;
  const int col0 = blockIdx.x * 128 + (wave & 1) * 64;
  const int l16 = lane & 15;
  const int quad = lane >> 4;

  floatx4 acc[4][4] = {};

  // fragment base: elem offset = (kb*N + row)*BK + quad*8
  const short* ap = cf + (size_t)(row0 + l16) * BK + quad * 8;
  const short* bp = cf + (size_t)(col0 + l16) * BK + quad * 8;

  bf16x8 a[4], bb[4];
  #pragma unroll
  for (int t = 0; t < 4; ++t) {
    a[t]  = *(const bf16x8*)(ap + (size_t)t * 16 * BK);
    bb[t] = *(const bf16x8*)(bp + (size_t)t * 16 * BK);
  }
  for (int kb = 0; kb < KB - 1; ++kb) {
    bf16x8 an[4], bn[4];
    size_t kofs = (size_t)(kb + 1) * N * BK;
    #pragma unroll
    for (int t = 0; t < 4; ++t) {
      an[t] = *(const bf16x8*)(ap + kofs + (size_t)t * 16 * BK);
      bn[t] = *(const bf16x8*)(bp + kofs + (size_t)t * 16 * BK);
    }
    #pragma unroll
    for (int rt = 0; rt < 4; ++rt)
      #pragma unroll
      for (int ct = 0; ct < 4; ++ct)
        acc[rt][ct] = __builtin_amdgcn_mfma_f32_16x16x32_bf16(a[rt], bb[ct], acc[rt][ct], 0, 0, 0);
    #pragma unroll
    for (int t = 0; t < 4; ++t) { a[t] = an[t]; bb[t] = bn[t]; }
  }
  #pragma unroll
  for (int rt = 0; rt < 4; ++rt)
    #pragma unroll
    for (int ct = 0; ct < 4; ++ct)
      acc[rt][ct] = __builtin_amdgcn_mfma_f32_16x16x32_bf16(a[rt], bb[ct], acc[rt][ct], 0, 0, 0);

  // Epilogue. C/D layout (verified round 1): col = lane&15, row = quad*4 + reg.
  const float invT = 1.0f / TEMP;
  int clab[4], colg[4];
  #pragma unroll
  for (int ct = 0; ct < 4; ++ct) {
    colg[ct] = col0 + ct * 16 + l16;
    clab[ct] = labels[colg[ct] & (B - 1)];
  }
  #pragma unroll
  for (int rt = 0; rt < 4; ++rt) {
    #pragma unroll
    for (int r = 0; r < 4; ++r) {
      int row = row0 + rt * 16 + quad * 4 + r;
      int rlab = labels[row & (B - 1)];
      float zs = 0.f, ps = 0.f;
      #pragma unroll
      for (int ct = 0; ct < 4; ++ct) {
        float sv = acc[rt][ct][r] * invT;
        if (colg[ct] != row) {
          zs += __expf(sv - invT);
          if (clab[ct] == rlab) ps += sv;
        }
      }
      #pragma unroll
      for (int mk = 1; mk < 16; mk <<= 1) {
        zs += __shfl_xor(zs, mk);
        ps += __shfl_xor(ps, mk);
      }
      if (l16 == 0) {
        atomicAdd(&Z[row], zs);
        atomicAdd(&P[row], ps);
      }
    }
  }

  // ---- fused finalize: last block to finish reduces 4096 rows -> loss ----
  __shared__ int isLast;
  __shared__ float red[4];
  __syncthreads();  // drains this block's atomics (vmcnt) before the counter
  if (threadIdx.x == 0) {
    __threadfence();
    unsigned old = __hip_atomic_fetch_add(counter, 1u, __ATOMIC_ACQ_REL,
                                          __HIP_MEMORY_SCOPE_AGENT);
    isLast = (old == (unsigned)(gridDim.x * gridDim.y - 1));
  }
  __syncthreads();
  if (isLast) {
    float accv = 0.f;
    for (int i = threadIdx.x; i < N; i += 256) {
      int b = i & (B - 1);
      float c = 2.f * (float)hist[labels[b]] - 1.f;  // positives excl. self
      float Zi = __hip_atomic_load(&Z[i], __ATOMIC_RELAXED, __HIP_MEMORY_SCOPE_AGENT);
      float Pi = __hip_atomic_load(&P[i], __ATOMIC_RELAXED, __HIP_MEMORY_SCOPE_AGENT);
      float lse = invT + logf(Zi);
      accv += modv[b] * (Pi - c * lse) / c;
    }
    #pragma unroll
    for (int m = 32; m; m >>= 1) accv += __shfl_xor(accv, m);
    if ((threadIdx.x & 63) == 0) red[threadIdx.x >> 6] = accv;
    __syncthreads();
    if (threadIdx.x == 0)
      out[0] = -(red[0] + red[1] + red[2] + red[3]) / (float)N;
  }
}

extern "C" void kernel_launch(void* const* d_in, const int* in_sizes, int n_in,
                              void* d_out, int out_size, void* d_ws, size_t ws_size,
                              hipStream_t stream) {
  const float* feat = (const float*)d_in[0];   // [B, V, D] fp32
  const float* preds = (const float*)d_in[1];  // [B, C] fp32
  const int* labels = (const int*)d_in[2];     // [B] int32
  float* out = (float*)d_out;

  char* ws = (char*)d_ws;
  float*    Z       = (float*)(ws);            // 4096 f32 = 16 KB
  float*    P       = (float*)(ws + 16384);    // 4096 f32 = 16 KB
  float*    modv    = (float*)(ws + 32768);    // 2048 f32 = 8 KB
  int*      hist    = (int*)  (ws + 40960);    // 1000 i32 ~ 4 KB
  unsigned* counter = (unsigned*)(ws + 44960); // 4 B
  short*    cf      = (short*)(ws + 49152);    // [8][4096][32] bf16 = 2 MB

  prep_kernel<<<1538, 256, 0, stream>>>(feat, preds, labels, cf, modv, hist,
                                        Z /* zero region start */, counter);
  dim3 grid(N / 128, N / 128);  // 32 x 32
  gram_kernel<<<grid, 256, 0, stream>>>(cf, labels, modv, hist, Z, P, counter, out);
}

// Round 3
// 139.376 us; speedup vs baseline: 1.0432x; 1.0432x over previous
//
#include <hip/hip_runtime.h>
#include <math.h>

// Problem constants (from reference setup_inputs)
#define TEMP 0.07f
constexpr int B = 2048;
constexpr int V = 2;
constexpr int D = 256;
constexpr int C = 1000;
constexpr int N = V * B;   // 4096
constexpr int BK = 32;     // K-tile width (elements)
constexpr int KB = D / BK; // 8 K-blocks
constexpr int CS = 16;             // column splits
constexpr int CPB = N / CS;        // 256 cols per block
constexpr int TPB = CPB / 16;      // 16 col-tiles per block
constexpr int RSTRIPS = N / 64;    // 64 row strips (64 rows per block, 16/wave)

typedef __attribute__((ext_vector_type(8))) short bf16x8;   // 8 bf16 (4 VGPRs)
typedef __attribute__((ext_vector_type(4))) float floatx4;  // MFMA accumulator

__device__ __forceinline__ short f2bf(float x) {
  union { float f; unsigned u; } v; v.f = x;
  unsigned r = v.u + 0x7FFF + ((v.u >> 16) & 1);  // round-to-nearest-even
  return (short)(r >> 16);
}

// ---------------------------------------------------------------------------
// prep kernel: block-range fused
//   [0, 1024)    : L2-normalize rows -> cf in K-tiled layout [kb][N][32] bf16
//   [1024, 1536) : per-sample focal modulation (softmax over preds)
//   1536         : label histogram + zero completion counter
// ---------------------------------------------------------------------------
__global__ __launch_bounds__(256) void prep_kernel(
    const float* __restrict__ feat, const float* __restrict__ preds,
    const int* __restrict__ labels, short* __restrict__ cf,
    float* __restrict__ modv, int* __restrict__ hist,
    unsigned* __restrict__ counter) {
  const int bid = blockIdx.x;
  const int tid = threadIdx.x;
  if (bid < 1024) {
    // ---- normalize: one wave per row i of cf ----
    int i = (bid << 2) | (tid >> 6);   // [0, 4096)
    int lane = tid & 63;
    int v = i >> 11;
    int b = i & (B - 1);
    const float* src = feat + (size_t)(b * V + v) * D;
    float4 x = ((const float4*)src)[lane];
    float ss = x.x * x.x + x.y * x.y + x.z * x.z + x.w * x.w;
    #pragma unroll
    for (int m = 32; m; m >>= 1) ss += __shfl_xor(ss, m);
    float inv = rsqrtf(ss);
    short4 o;
    o.x = f2bf(x.x * inv); o.y = f2bf(x.y * inv);
    o.z = f2bf(x.z * inv); o.w = f2bf(x.w * inv);
    // K-tiled layout: elem offset = (kb*N + i)*BK + k_in_block
    // lane holds k = 4*lane .. 4*lane+3  ->  kb = lane>>3, k_in = (lane&7)*4
    size_t off = ((size_t)(lane >> 3) * N + i) * BK + (lane & 7) * 4;
    *(short4*)(cf + off) = o;
  } else if (bid < 1536) {
    // ---- focal modulation: one wave per sample b ----
    int b = ((bid - 1024) << 2) | (tid >> 6);  // [0, 2048)
    int lane = tid & 63;
    const float* p = preds + (size_t)b * C;
    float m = -1e30f;
    for (int j = lane; j < C; j += 64) m = fmaxf(m, p[j]);
    #pragma unroll
    for (int mk = 32; mk; mk >>= 1) m = fmaxf(m, __shfl_xor(m, mk));
    float s = 0.f;
    for (int j = lane; j < C; j += 64) s += __expf(p[j] - m);
    #pragma unroll
    for (int mk = 32; mk; mk >>= 1) s += __shfl_xor(s, mk);
    int lab = labels[b];
    float nll = p[lab] - (m + logf(s));  // log p_t
    float pt = __expf(nll);
    float md = 1.f - pt;
    md = md * md;  // gamma = 2
    if (lane == 0) modv[b] = md;
  } else {
    // ---- label histogram + counter zero ----
    __shared__ int h[C];
    for (int t = tid; t < C; t += 256) h[t] = 0;
    __syncthreads();
    for (int t = tid; t < B; t += 256) atomicAdd(&h[labels[t]], 1);
    __syncthreads();
    for (int t = tid; t < C; t += 256) hist[t] = h[t];
    if (tid == 0) *counter = 0u;
  }
}

// ---------------------------------------------------------------------------
// strip kernel: S = cf*cf^T / T, row-strip x column-loop, NO atomicAdds.
// Block (rs, cs): rows [rs*64, rs*64+64), cols [cs*256, cs*256+256).
// Wave w owns rows rs*64 + w*16 + [0,16) exclusively: A-frags (16 x 256 K)
// live in 32 VGPRs for the kernel's lifetime; Z/P accumulate in registers
// across the 16-col-tile loop; one relaxed store per (row, col-split) at the
// end into partial arrays Zp/Pp[cs][N]. Last block reduces partials -> loss.
// Fixed LSE shift 1/T is valid since rows are unit vectors (s_ij <= 1/T).
// ---------------------------------------------------------------------------
__global__ __launch_bounds__(256) void strip_kernel(
    const short* __restrict__ cf, const int* __restrict__ labels,
    const float* __restrict__ modv, const int* __restrict__ hist,
    float* __restrict__ Zp, float* __restrict__ Pp,
    unsigned* __restrict__ counter, float* __restrict__ out) {
  const int lane = threadIdx.x & 63;
  const int wave = threadIdx.x >> 6;
  const int l16 = lane & 15;
  const int quad = lane >> 4;
  const int rs = blockIdx.x;
  const int cs = blockIdx.y;
  const int row0 = rs * 64 + wave * 16;
  const int col0 = cs * CPB;

  // A fragments: this wave's 16 rows, all of K. Coalesced 1KB spans.
  bf16x8 A[KB];
  const short* ap = cf + (size_t)(row0 + l16) * BK + quad * 8;
  #pragma unroll
  for (int kb = 0; kb < KB; ++kb)
    A[kb] = *(const bf16x8*)(ap + (size_t)kb * N * BK);

  int rowl[4], rlab[4];
  #pragma unroll
  for (int e = 0; e < 4; ++e) {
    rowl[e] = row0 + quad * 4 + e;   // C/D layout: row = quad*4 + reg
    rlab[e] = labels[rowl[e] & (B - 1)];
  }

  const float invT = 1.0f / TEMP;
  float zs[4] = {0.f, 0.f, 0.f, 0.f};
  float ps[4] = {0.f, 0.f, 0.f, 0.f};

  const short* bp0 = cf + (size_t)(col0 + l16) * BK + quad * 8;
  bf16x8 Bc[KB], Bn[KB];
  #pragma unroll
  for (int kb = 0; kb < KB; ++kb)
    Bc[kb] = *(const bf16x8*)(bp0 + (size_t)kb * N * BK);

  for (int t = 0; t < TPB; ++t) {
    if (t + 1 < TPB) {
      const short* bp = bp0 + (size_t)(t + 1) * 16 * BK;
      #pragma unroll
      for (int kb = 0; kb < KB; ++kb)
        Bn[kb] = *(const bf16x8*)(bp + (size_t)kb * N * BK);
    }
    floatx4 acc = {0.f, 0.f, 0.f, 0.f};
    #pragma unroll
    for (int kb = 0; kb < KB; ++kb)
      acc = __builtin_amdgcn_mfma_f32_16x16x32_bf16(A[kb], Bc[kb], acc, 0, 0, 0);

    int col = col0 + t * 16 + l16;   // C/D layout: col = lane & 15
    int clab = labels[col & (B - 1)];
    #pragma unroll
    for (int e = 0; e < 4; ++e) {
      float sv = acc[e] * invT;
      if (col != rowl[e]) {
        zs[e] += __expf(sv - invT);
        if (clab == rlab[e]) ps[e] += sv;
      }
    }
    #pragma unroll
    for (int kb = 0; kb < KB; ++kb) Bc[kb] = Bn[kb];
  }

  // reduce across the 16 lanes sharing each row (xor masks stay in-group)
  #pragma unroll
  for (int e = 0; e < 4; ++e) {
    #pragma unroll
    for (int mk = 1; mk < 16; mk <<= 1) {
      zs[e] += __shfl_xor(zs[e], mk);
      ps[e] += __shfl_xor(ps[e], mk);
    }
  }
  if (l16 == 0) {
    #pragma unroll
    for (int e = 0; e < 4; ++e) {
      __hip_atomic_store(&Zp[(size_t)cs * N + rowl[e]], zs[e],
                         __ATOMIC_RELAXED, __HIP_MEMORY_SCOPE_AGENT);
      __hip_atomic_store(&Pp[(size_t)cs * N + rowl[e]], ps[e],
                         __ATOMIC_RELAXED, __HIP_MEMORY_SCOPE_AGENT);
    }
  }

  // ---- fused finalize: last block reduces 16 partials per row -> loss ----
  __shared__ int isLast;
  __shared__ float red[4];
  __syncthreads();  // all waves' stores issued before the counter bump
  if (threadIdx.x == 0) {
    unsigned old = __hip_atomic_fetch_add(counter, 1u, __ATOMIC_ACQ_REL,
                                          __HIP_MEMORY_SCOPE_AGENT);
    isLast = (old == (unsigned)(gridDim.x * gridDim.y - 1));
  }
  __syncthreads();
  if (isLast) {
    float accv = 0.f;
    const int tid = threadIdx.x;
    for (int i4 = tid * 4; i4 < N; i4 += 1024) {
      float4 Z4 = {0.f, 0.f, 0.f, 0.f}, P4 = {0.f, 0.f, 0.f, 0.f};
      #pragma unroll
      for (int c2 = 0; c2 < CS; ++c2) {
        float4 z = *(const float4*)&Zp[(size_t)c2 * N + i4];
        float4 p = *(const float4*)&Pp[(size_t)c2 * N + i4];
        Z4.x += z.x; Z4.y += z.y; Z4.z += z.z; Z4.w += z.w;
        P4.x += p.x; P4.y += p.y; P4.z += p.z; P4.w += p.w;
      }
      float Zi[4] = {Z4.x, Z4.y, Z4.z, Z4.w};
      float Pi[4] = {P4.x, P4.y, P4.z, P4.w};
      #pragma unroll
      for (int e = 0; e < 4; ++e) {
        int i = i4 + e;
        int b = i & (B - 1);
        float c = 2.f * (float)hist[labels[b]] - 1.f;  // positives excl. self
        float lse = invT + logf(Zi[e]);
        accv += modv[b] * (Pi[e] - c * lse) / c;
      }
    }
    #pragma unroll
    for (int m = 32; m; m >>= 1) accv += __shfl_xor(accv, m);
    if ((threadIdx.x & 63) == 0) red[threadIdx.x >> 6] = accv;
    __syncthreads();
    if (threadIdx.x == 0)
      out[0] = -(red[0] + red[1] + red[2] + red[3]) / (float)N;
  }
}

extern "C" void kernel_launch(void* const* d_in, const int* in_sizes, int n_in,
                              void* d_out, int out_size, void* d_ws, size_t ws_size,
                              hipStream_t stream) {
  const float* feat = (const float*)d_in[0];   // [B, V, D] fp32
  const float* preds = (const float*)d_in[1];  // [B, C] fp32
  const int* labels = (const int*)d_in[2];     // [B] int32
  float* out = (float*)d_out;

  char* ws = (char*)d_ws;
  float*    modv    = (float*)(ws);            // 2048 f32 = 8 KB
  int*      hist    = (int*)  (ws + 8192);     // 1000 i32 ~ 4 KB
  unsigned* counter = (unsigned*)(ws + 12288); // 4 B
  float*    Zp      = (float*)(ws + 16384);    // [16][4096] f32 = 256 KB
  float*    Pp      = (float*)(ws + 16384 + 262144);       // 256 KB
  short*    cf      = (short*)(ws + 16384 + 524288);       // [8][4096][32] bf16 = 2 MB

  prep_kernel<<<1537, 256, 0, stream>>>(feat, preds, labels, cf, modv, hist,
                                        counter);
  dim3 grid(RSTRIPS, CS);  // 64 x 16 = 1024 blocks
  strip_kernel<<<grid, 256, 0, stream>>>(cf, labels, modv, hist, Zp, Pp,
                                         counter, out);
}

// Round 5
// 138.277 us; speedup vs baseline: 1.0514x; 1.0079x over previous
//
#include <hip/hip_runtime.h>
#include <math.h>

// Problem constants (from reference setup_inputs)
#define TEMP 0.07f
constexpr int B = 2048;
constexpr int V = 2;
constexpr int D = 256;
constexpr int C = 1000;
constexpr int N = V * B;   // 4096
constexpr int BK = 32;     // K-tile width (elements)
constexpr int KB = D / BK; // 8 K-blocks
constexpr int CS = 16;             // column splits
constexpr int CPB = N / CS;        // 256 cols per block
constexpr int TPB = CPB / 16;      // 16 col-tiles per block
constexpr int RSTRIPS = N / 64;    // 64 row strips (64 rows per block, 16/wave)

typedef __attribute__((ext_vector_type(8))) short bf16x8;   // 8 bf16 (4 VGPRs)
typedef __attribute__((ext_vector_type(4))) short short4n;  // native 4-short vec
typedef __attribute__((ext_vector_type(4))) float floatx4;  // MFMA accumulator

__device__ __forceinline__ short f2bf(float x) {
  union { float f; unsigned u; } v; v.f = x;
  unsigned r = v.u + 0x7FFF + ((v.u >> 16) & 1);  // round-to-nearest-even
  return (short)(r >> 16);
}

// ---------------------------------------------------------------------------
// prep kernel: block-range fused
//   [0, 1024)    : L2-normalize rows -> cf in K-tiled layout [kb][N][32] bf16
//                  *** cf written with NONTEMPORAL stores: stream past the
//                  writer CU's XCD-private L2 so the gram kernel's grid-wide
//                  reads hit CLEAN lines (no cross-XCD dirty-probe path). ***
//   [1024, 1536) : per-sample focal modulation (softmax over preds)
//   1536         : label histogram + zero completion counter
// ---------------------------------------------------------------------------
__global__ __launch_bounds__(256) void prep_kernel(
    const float* __restrict__ feat, const float* __restrict__ preds,
    const int* __restrict__ labels, short* __restrict__ cf,
    float* __restrict__ modv, int* __restrict__ hist,
    unsigned* __restrict__ counter) {
  const int bid = blockIdx.x;
  const int tid = threadIdx.x;
  if (bid < 1024) {
    // ---- normalize: one wave per row i of cf ----
    int i = (bid << 2) | (tid >> 6);   // [0, 4096)
    int lane = tid & 63;
    int v = i >> 11;
    int b = i & (B - 1);
    const float* src = feat + (size_t)(b * V + v) * D;
    float4 x = ((const float4*)src)[lane];
    float ss = x.x * x.x + x.y * x.y + x.z * x.z + x.w * x.w;
    #pragma unroll
    for (int m = 32; m; m >>= 1) ss += __shfl_xor(ss, m);
    float inv = rsqrtf(ss);
    short4n o;
    o.x = f2bf(x.x * inv); o.y = f2bf(x.y * inv);
    o.z = f2bf(x.z * inv); o.w = f2bf(x.w * inv);
    // K-tiled layout: elem offset = (kb*N + i)*BK + k_in_block
    // lane holds k = 4*lane .. 4*lane+3  ->  kb = lane>>3, k_in = (lane&7)*4
    size_t off = ((size_t)(lane >> 3) * N + i) * BK + (lane & 7) * 4;
    __builtin_nontemporal_store(o, (short4n*)(cf + off));
  } else if (bid < 1536) {
    // ---- focal modulation: one wave per sample b ----
    int b = ((bid - 1024) << 2) | (tid >> 6);  // [0, 2048)
    int lane = tid & 63;
    const float* p = preds + (size_t)b * C;
    float m = -1e30f;
    for (int j = lane; j < C; j += 64) m = fmaxf(m, p[j]);
    #pragma unroll
    for (int mk = 32; mk; mk >>= 1) m = fmaxf(m, __shfl_xor(m, mk));
    float s = 0.f;
    for (int j = lane; j < C; j += 64) s += __expf(p[j] - m);
    #pragma unroll
    for (int mk = 32; mk; mk >>= 1) s += __shfl_xor(s, mk);
    int lab = labels[b];
    float nll = p[lab] - (m + logf(s));  // log p_t
    float pt = __expf(nll);
    float md = 1.f - pt;
    md = md * md;  // gamma = 2
    if (lane == 0) __builtin_nontemporal_store(md, &modv[b]);
  } else {
    // ---- label histogram + counter zero ----
    __shared__ int h[C];
    for (int t = tid; t < C; t += 256) h[t] = 0;
    __syncthreads();
    for (int t = tid; t < B; t += 256) atomicAdd(&h[labels[t]], 1);
    __syncthreads();
    for (int t = tid; t < C; t += 256) __builtin_nontemporal_store(h[t], &hist[t]);
    if (tid == 0) *counter = 0u;
  }
}

// ---------------------------------------------------------------------------
// strip kernel: UNCHANGED from round 3 (controlled experiment: only the
// memory state of cf differs — clean vs dirty-in-remote-L2).
// S = cf*cf^T / T, row-strip x column-loop, no atomics.
// ---------------------------------------------------------------------------
__global__ __launch_bounds__(256) void strip_kernel(
    const short* __restrict__ cf, const int* __restrict__ labels,
    const float* __restrict__ modv, const int* __restrict__ hist,
    float* __restrict__ Zp, float* __restrict__ Pp,
    unsigned* __restrict__ counter, float* __restrict__ out) {
  const int lane = threadIdx.x & 63;
  const int wave = threadIdx.x >> 6;
  const int l16 = lane & 15;
  const int quad = lane >> 4;
  const int rs = blockIdx.x;
  const int cs = blockIdx.y;
  const int row0 = rs * 64 + wave * 16;
  const int col0 = cs * CPB;

  // A fragments: this wave's 16 rows, all of K. Coalesced 1KB spans.
  bf16x8 A[KB];
  const short* ap = cf + (size_t)(row0 + l16) * BK + quad * 8;
  #pragma unroll
  for (int kb = 0; kb < KB; ++kb)
    A[kb] = *(const bf16x8*)(ap + (size_t)kb * N * BK);

  int rowl[4], rlab[4];
  #pragma unroll
  for (int e = 0; e < 4; ++e) {
    rowl[e] = row0 + quad * 4 + e;   // C/D layout: row = quad*4 + reg
    rlab[e] = labels[rowl[e] & (B - 1)];
  }

  const float invT = 1.0f / TEMP;
  float zs[4] = {0.f, 0.f, 0.f, 0.f};
  float ps[4] = {0.f, 0.f, 0.f, 0.f};

  const short* bp0 = cf + (size_t)(col0 + l16) * BK + quad * 8;
  bf16x8 Bc[KB], Bn[KB];
  #pragma unroll
  for (int kb = 0; kb < KB; ++kb)
    Bc[kb] = *(const bf16x8*)(bp0 + (size_t)kb * N * BK);

  for (int t = 0; t < TPB; ++t) {
    if (t + 1 < TPB) {
      const short* bp = bp0 + (size_t)(t + 1) * 16 * BK;
      #pragma unroll
      for (int kb = 0; kb < KB; ++kb)
        Bn[kb] = *(const bf16x8*)(bp + (size_t)kb * N * BK);
    }
    floatx4 acc = {0.f, 0.f, 0.f, 0.f};
    #pragma unroll
    for (int kb = 0; kb < KB; ++kb)
      acc = __builtin_amdgcn_mfma_f32_16x16x32_bf16(A[kb], Bc[kb], acc, 0, 0, 0);

    int col = col0 + t * 16 + l16;   // C/D layout: col = lane & 15
    int clab = labels[col & (B - 1)];
    #pragma unroll
    for (int e = 0; e < 4; ++e) {
      float sv = acc[e] * invT;
      if (col != rowl[e]) {
        zs[e] += __expf(sv - invT);
        if (clab == rlab[e]) ps[e] += sv;
      }
    }
    #pragma unroll
    for (int kb = 0; kb < KB; ++kb) Bc[kb] = Bn[kb];
  }

  // reduce across the 16 lanes sharing each row (xor masks stay in-group)
  #pragma unroll
  for (int e = 0; e < 4; ++e) {
    #pragma unroll
    for (int mk = 1; mk < 16; mk <<= 1) {
      zs[e] += __shfl_xor(zs[e], mk);
      ps[e] += __shfl_xor(ps[e], mk);
    }
  }
  if (l16 == 0) {
    #pragma unroll
    for (int e = 0; e < 4; ++e) {
      __hip_atomic_store(&Zp[(size_t)cs * N + rowl[e]], zs[e],
                         __ATOMIC_RELAXED, __HIP_MEMORY_SCOPE_AGENT);
      __hip_atomic_store(&Pp[(size_t)cs * N + rowl[e]], ps[e],
                         __ATOMIC_RELAXED, __HIP_MEMORY_SCOPE_AGENT);
    }
  }

  // ---- fused finalize: last block reduces 16 partials per row -> loss ----
  __shared__ int isLast;
  __shared__ float red[4];
  __syncthreads();  // all waves' stores issued before the counter bump
  if (threadIdx.x == 0) {
    unsigned old = __hip_atomic_fetch_add(counter, 1u, __ATOMIC_ACQ_REL,
                                          __HIP_MEMORY_SCOPE_AGENT);
    isLast = (old == (unsigned)(gridDim.x * gridDim.y - 1));
  }
  __syncthreads();
  if (isLast) {
    float accv = 0.f;
    const int tid = threadIdx.x;
    for (int i4 = tid * 4; i4 < N; i4 += 1024) {
      float4 Z4 = {0.f, 0.f, 0.f, 0.f}, P4 = {0.f, 0.f, 0.f, 0.f};
      #pragma unroll
      for (int c2 = 0; c2 < CS; ++c2) {
        float4 z = *(const float4*)&Zp[(size_t)c2 * N + i4];
        float4 p = *(const float4*)&Pp[(size_t)c2 * N + i4];
        Z4.x += z.x; Z4.y += z.y; Z4.z += z.z; Z4.w += z.w;
        P4.x += p.x; P4.y += p.y; P4.z += p.z; P4.w += p.w;
      }
      float Zi[4] = {Z4.x, Z4.y, Z4.z, Z4.w};
      float Pi[4] = {P4.x, P4.y, P4.z, P4.w};
      #pragma unroll
      for (int e = 0; e < 4; ++e) {
        int i = i4 + e;
        int b = i & (B - 1);
        float c = 2.f * (float)hist[labels[b]] - 1.f;  // positives excl. self
        float lse = invT + logf(Zi[e]);
        accv += modv[b] * (Pi[e] - c * lse) / c;
      }
    }
    #pragma unroll
    for (int m = 32; m; m >>= 1) accv += __shfl_xor(accv, m);
    if ((threadIdx.x & 63) == 0) red[threadIdx.x >> 6] = accv;
    __syncthreads();
    if (threadIdx.x == 0)
      out[0] = -(red[0] + red[1] + red[2] + red[3]) / (float)N;
  }
}

extern "C" void kernel_launch(void* const* d_in, const int* in_sizes, int n_in,
                              void* d_out, int out_size, void* d_ws, size_t ws_size,
                              hipStream_t stream) {
  const float* feat = (const float*)d_in[0];   // [B, V, D] fp32
  const float* preds = (const float*)d_in[1];  // [B, C] fp32
  const int* labels = (const int*)d_in[2];     // [B] int32
  float* out = (float*)d_out;

  char* ws = (char*)d_ws;
  float*    modv    = (float*)(ws);            // 2048 f32 = 8 KB
  int*      hist    = (int*)  (ws + 8192);     // 1000 i32 ~ 4 KB
  unsigned* counter = (unsigned*)(ws + 12288); // 4 B
  float*    Zp      = (float*)(ws + 16384);    // [16][4096] f32 = 256 KB
  float*    Pp      = (float*)(ws + 16384 + 262144);       // 256 KB
  short*    cf      = (short*)(ws + 16384 + 524288);       // [8][4096][32] bf16 = 2 MB

  prep_kernel<<<1537, 256, 0, stream>>>(feat, preds, labels, cf, modv, hist,
                                        counter);
  dim3 grid(RSTRIPS, CS);  // 64 x 16 = 1024 blocks
  strip_kernel<<<grid, 256, 0, stream>>>(cf, labels, modv, hist, Zp, Pp,
                                         counter, out);
}

// Round 6
// 108.351 us; speedup vs baseline: 1.3419x; 1.2762x over previous
//
#include <hip/hip_runtime.h>
#include <math.h>

// Problem constants (from reference setup_inputs)
#define TEMP 0.07f
constexpr int B = 2048;
constexpr int V = 2;
constexpr int D = 256;   // K
constexpr int C = 1000;
constexpr int N = V * B; // 4096
constexpr int BK = 64;   // K-tile (elements) per staging iter
constexpr int NKI = D / BK;  // 4 K-iterations

typedef __attribute__((ext_vector_type(8))) short bf16x8;   // 8 bf16 (4 VGPRs)
typedef __attribute__((ext_vector_type(4))) short short4n;  // native 4-short vec
typedef __attribute__((ext_vector_type(4))) float floatx4;  // MFMA accumulator
typedef unsigned int u32;

__device__ __forceinline__ short f2bf(float x) {
  union { float f; unsigned u; } v; v.f = x;
  unsigned r = v.u + 0x7FFF + ((v.u >> 16) & 1);  // round-to-nearest-even
  return (short)(r >> 16);
}

// async global->LDS, 16B per lane. LDS dest is wave-uniform base + lane*16
// (m104/m108), so the *source* address carries the swizzle.
__device__ __forceinline__ void gload_lds16(const short* g, short* l) {
  __builtin_amdgcn_global_load_lds(
      (const __attribute__((address_space(1))) u32*)g,
      (__attribute__((address_space(3))) u32*)l, 16, 0, 0);
}

// ---------------------------------------------------------------------------
// prep kernel (block-range fused):
//   [0,1024)   : L2-normalize rows -> cf row-major [N][D] bf16 (coalesced)
//   [1024,1536): per-sample focal modulation (softmax over preds)
//   1536       : label histogram + zero out[0]
// ---------------------------------------------------------------------------
__global__ __launch_bounds__(256) void prep_kernel(
    const float* __restrict__ feat, const float* __restrict__ preds,
    const int* __restrict__ labels, short* __restrict__ cf,
    float* __restrict__ modv, int* __restrict__ hist,
    float* __restrict__ out) {
  const int bid = blockIdx.x;
  const int tid = threadIdx.x;
  if (bid < 1024) {
    int i = (bid << 2) | (tid >> 6);   // row of cf, [0, 4096)
    int lane = tid & 63;
    int v = i >> 11;
    int b = i & (B - 1);
    const float* src = feat + (size_t)(b * V + v) * D;
    float4 x = ((const float4*)src)[lane];
    float ss = x.x * x.x + x.y * x.y + x.z * x.z + x.w * x.w;
    #pragma unroll
    for (int m = 32; m; m >>= 1) ss += __shfl_xor(ss, m);
    float inv = rsqrtf(ss);
    short4n o;
    o.x = f2bf(x.x * inv); o.y = f2bf(x.y * inv);
    o.z = f2bf(x.z * inv); o.w = f2bf(x.w * inv);
    *(short4n*)(cf + (size_t)i * D + lane * 4) = o;   // row-major, coalesced
  } else if (bid < 1536) {
    int b = ((bid - 1024) << 2) | (tid >> 6);  // [0, 2048)
    int lane = tid & 63;
    const float* p = preds + (size_t)b * C;
    float m = -1e30f;
    for (int j = lane; j < C; j += 64) m = fmaxf(m, p[j]);
    #pragma unroll
    for (int mk = 32; mk; mk >>= 1) m = fmaxf(m, __shfl_xor(m, mk));
    float s = 0.f;
    for (int j = lane; j < C; j += 64) s += __expf(p[j] - m);
    #pragma unroll
    for (int mk = 32; mk; mk >>= 1) s += __shfl_xor(s, mk);
    int lab = labels[b];
    float nll = p[lab] - (m + logf(s));  // log p_t
    float pt = __expf(nll);
    float md = 1.f - pt;
    md = md * md;  // gamma = 2
    if (lane == 0) modv[b] = md;
  } else {
    __shared__ int h[C];
    for (int t = tid; t < C; t += 256) h[t] = 0;
    __syncthreads();
    for (int t = tid; t < B; t += 256) atomicAdd(&h[labels[t]], 1);
    __syncthreads();
    for (int t = tid; t < C; t += 256) hist[t] = h[t];
    if (tid == 0) out[0] = 0.f;   // finalize atomicAdds onto this
  }
}

// ---------------------------------------------------------------------------
// gemm kernel: m97-style LDS-staged 128x128 tile, BK=64, single-buffered.
// Swizzled staging: global 16B-chunk c of row r lands at LDS slot
// r*8 + (c ^ (r&7)); readers apply the same swizzle -> ds_read_b128 spreads
// across all 32 banks (2-way aliasing only, free per m136).
// Fused epilogue per block: Z/P partials per (col-block, row), no atomics.
//   Z[i] = sum_{j!=i} exp(s_ij - 1/T)  (1/T valid shift: rows unit-norm)
//   P[i] = sum_{j!=i, label match} s_ij
// ---------------------------------------------------------------------------
__global__ __launch_bounds__(256) void gemm_kernel(
    const short* __restrict__ cf, const int* __restrict__ labels,
    float* __restrict__ Zp, float* __restrict__ Pp) {
  __shared__ short smem[2 * 128 * BK];     // A tile | B tile, 16KB each
  short* At = smem;
  short* Bt = smem + 128 * BK;

  const int tid = threadIdx.x;
  const int lane = tid & 63;
  const int wave = tid >> 6;
  const int l16 = lane & 15;
  const int quad = lane >> 4;
  const int row0g = blockIdx.y * 128;
  const int col0g = blockIdx.x * 128;
  const int rw0 = (wave >> 1) * 64;        // wave's row-quadrant in tile
  const int cw0 = (wave & 1) * 64;         // wave's col-quadrant in tile

  floatx4 acc[4][4] = {};

  for (int it = 0; it < NKI; ++it) {
    const int ko = it * BK;                // K offset (elements)
    if (it) __syncthreads();               // prev iter's reads done
    // stage A and B tiles: 4 issues each, 256 lanes x 16B per issue
    #pragma unroll
    for (int n = 0; n < 4; ++n) {
      int s = n * 256 + tid;               // LDS 16B-slot index [0,1024)
      int r = s >> 3;                      // tile row 0..127
      int cs = s & 7;                      // swizzled chunk position
      int c = cs ^ (r & 7);                // source chunk within row
      gload_lds16(cf + (size_t)(row0g + r) * D + ko + c * 8, At + s * 8);
      gload_lds16(cf + (size_t)(col0g + r) * D + ko + c * 8, Bt + s * 8);
    }
    asm volatile("s_waitcnt vmcnt(0)" ::: "memory");
    __syncthreads();
    // compute: 2 k-steps of 32 within the 64-wide tile
    #pragma unroll
    for (int ks8 = 0; ks8 < 8; ks8 += 4) { // chunk base: 0 (k=0..31), 4 (k=32..63)
      bf16x8 a[4], b[4];
      #pragma unroll
      for (int t = 0; t < 4; ++t) {
        int ra = rw0 + t * 16 + l16;
        int ca = (ks8 + quad) ^ (ra & 7);
        a[t] = *(const bf16x8*)(At + (ra * 8 + ca) * 8);
        int rb = cw0 + t * 16 + l16;
        int cb = (ks8 + quad) ^ (rb & 7);
        b[t] = *(const bf16x8*)(Bt + (rb * 8 + cb) * 8);
      }
      #pragma unroll
      for (int rt = 0; rt < 4; ++rt)
        #pragma unroll
        for (int ct = 0; ct < 4; ++ct)
          acc[rt][ct] = __builtin_amdgcn_mfma_f32_16x16x32_bf16(a[rt], b[ct], acc[rt][ct], 0, 0, 0);
    }
  }

  // ---- epilogue: exp/mask/reduce; C/D layout col=lane&15, row=quad*4+reg ----
  const float invT = 1.0f / TEMP;
  int clab[4], colg[4];
  #pragma unroll
  for (int ct = 0; ct < 4; ++ct) {
    colg[ct] = col0g + cw0 + ct * 16 + l16;
    clab[ct] = labels[colg[ct] & (B - 1)];
  }
  float zs[4][4], ps[4][4];                // [rt][e]
  #pragma unroll
  for (int rt = 0; rt < 4; ++rt) {
    #pragma unroll
    for (int e = 0; e < 4; ++e) {
      int row = row0g + rw0 + rt * 16 + quad * 4 + e;
      int rlab = labels[row & (B - 1)];
      float z = 0.f, p = 0.f;
      #pragma unroll
      for (int ct = 0; ct < 4; ++ct) {
        float sv = acc[rt][ct][e] * invT;
        if (colg[ct] != row) {
          z += __expf(sv - invT);
          if (clab[ct] == rlab) p += sv;
        }
      }
      #pragma unroll
      for (int mk = 1; mk < 16; mk <<= 1) {
        z += __shfl_xor(z, mk);
        p += __shfl_xor(p, mk);
      }
      zs[rt][e] = z; ps[rt][e] = p;        // valid in l16==0 lanes
    }
  }

  // combine the two col-half waves (w, w^1 share rows) via LDS, store once
  __syncthreads();                          // done with tiles; reuse smem
  float* Zl = (float*)smem;                 // [128] rows (col-half 1)
  float* Pl = Zl + 128;
  if ((wave & 1) && l16 == 0) {
    #pragma unroll
    for (int rt = 0; rt < 4; ++rt)
      #pragma unroll
      for (int e = 0; e < 4; ++e) {
        int rloc = rw0 + rt * 16 + quad * 4 + e;
        Zl[rloc] = zs[rt][e];
        Pl[rloc] = ps[rt][e];
      }
  }
  __syncthreads();
  if (!(wave & 1) && l16 == 0) {
    const int cb = blockIdx.x;              // col-block 0..31
    #pragma unroll
    for (int rt = 0; rt < 4; ++rt)
      #pragma unroll
      for (int e = 0; e < 4; ++e) {
        int rloc = rw0 + rt * 16 + quad * 4 + e;
        int grow = row0g + rloc;
        Zp[(size_t)cb * N + grow] = zs[rt][e] + Zl[rloc];
        Pp[(size_t)cb * N + grow] = ps[rt][e] + Pl[rloc];
      }
  }
}

// ---------------------------------------------------------------------------
// finalize: one row per thread, 16 blocks; atomicAdd block partials to out.
// ---------------------------------------------------------------------------
__global__ __launch_bounds__(256) void finalize_kernel(
    const float* __restrict__ Zp, const float* __restrict__ Pp,
    const float* __restrict__ modv, const int* __restrict__ hist,
    const int* __restrict__ labels, float* __restrict__ out) {
  __shared__ float red[4];
  const int i = blockIdx.x * 256 + threadIdx.x;   // row [0, 4096)
  float Zi = 0.f, Pi = 0.f;
  #pragma unroll
  for (int cb = 0; cb < 32; ++cb) {
    Zi += Zp[(size_t)cb * N + i];
    Pi += Pp[(size_t)cb * N + i];
  }
  int b = i & (B - 1);
  float c = 2.f * (float)hist[labels[b]] - 1.f;   // positives excl. self
  float lse = (1.0f / TEMP) + logf(Zi);
  float accv = modv[b] * (Pi - c * lse) / c;
  #pragma unroll
  for (int m = 32; m; m >>= 1) accv += __shfl_xor(accv, m);
  if ((threadIdx.x & 63) == 0) red[threadIdx.x >> 6] = accv;
  __syncthreads();
  if (threadIdx.x == 0)
    atomicAdd(out, -(red[0] + red[1] + red[2] + red[3]) / (float)N);
}

extern "C" void kernel_launch(void* const* d_in, const int* in_sizes, int n_in,
                              void* d_out, int out_size, void* d_ws, size_t ws_size,
                              hipStream_t stream) {
  const float* feat = (const float*)d_in[0];   // [B, V, D] fp32
  const float* preds = (const float*)d_in[1];  // [B, C] fp32
  const int* labels = (const int*)d_in[2];     // [B] int32
  float* out = (float*)d_out;

  char* ws = (char*)d_ws;
  float* modv = (float*)(ws);                  // 8 KB
  int*   hist = (int*)  (ws + 8192);           // ~4 KB
  float* Zp   = (float*)(ws + 16384);          // [32][4096] f32 = 512 KB
  float* Pp   = (float*)(ws + 16384 + 524288); // 512 KB
  short* cf   = (short*)(ws + 16384 + 1048576);// [4096][256] bf16 = 2 MB

  prep_kernel<<<1537, 256, 0, stream>>>(feat, preds, labels, cf, modv, hist, out);
  dim3 grid(N / 128, N / 128);  // 32 x 32
  gemm_kernel<<<grid, 256, 0, stream>>>(cf, labels, Zp, Pp);
  finalize_kernel<<<16, 256, 0, stream>>>(Zp, Pp, modv, hist, labels, out);
}

// Round 7
// 91.346 us; speedup vs baseline: 1.5916x; 1.1862x over previous
//
#include <hip/hip_runtime.h>
#include <math.h>

// Problem constants (from reference setup_inputs)
#define TEMP 0.07f
constexpr int B = 2048;
constexpr int V = 2;
constexpr int D = 256;   // K
constexpr int C = 1000;
constexpr int N = V * B; // 4096
constexpr int BK = 64;   // K-tile (elements) per staging iter
constexpr int NKI = D / BK;           // 4 K-iterations
constexpr int NSTRIP = N / 128;       // 32 row/col strips
constexpr int NBLK = NSTRIP * (NSTRIP + 1) / 2;  // 528 upper-triangle blocks

typedef __attribute__((ext_vector_type(8))) short bf16x8;   // 8 bf16 (4 VGPRs)
typedef __attribute__((ext_vector_type(4))) short short4n;  // native 4-short vec
typedef __attribute__((ext_vector_type(4))) float floatx4;  // MFMA accumulator
typedef unsigned int u32;

__device__ __forceinline__ short f2bf(float x) {
  union { float f; unsigned u; } v; v.f = x;
  unsigned r = v.u + 0x7FFF + ((v.u >> 16) & 1);  // round-to-nearest-even
  return (short)(r >> 16);
}

// async global->LDS, 16B per lane. LDS dest is wave-uniform base + lane*16
// (m104/m108), so the *source* address carries the swizzle.
__device__ __forceinline__ void gload_lds16(const short* g, short* l) {
  __builtin_amdgcn_global_load_lds(
      (const __attribute__((address_space(1))) u32*)g,
      (__attribute__((address_space(3))) u32*)l, 16, 0, 0);
}

// ---------------------------------------------------------------------------
// prep kernel (block-range fused):
//   [0,1024)   : L2-normalize rows -> cf row-major [N][D] bf16 (coalesced)
//   [1024,1536): per-sample focal modulation (softmax over preds)
//   1536       : label histogram + zero out[0]
// ---------------------------------------------------------------------------
__global__ __launch_bounds__(256) void prep_kernel(
    const float* __restrict__ feat, const float* __restrict__ preds,
    const int* __restrict__ labels, short* __restrict__ cf,
    float* __restrict__ modv, int* __restrict__ hist,
    float* __restrict__ out) {
  const int bid = blockIdx.x;
  const int tid = threadIdx.x;
  if (bid < 1024) {
    int i = (bid << 2) | (tid >> 6);   // row of cf, [0, 4096)
    int lane = tid & 63;
    int v = i >> 11;
    int b = i & (B - 1);
    const float* src = feat + (size_t)(b * V + v) * D;
    float4 x = ((const float4*)src)[lane];
    float ss = x.x * x.x + x.y * x.y + x.z * x.z + x.w * x.w;
    #pragma unroll
    for (int m = 32; m; m >>= 1) ss += __shfl_xor(ss, m);
    float inv = rsqrtf(ss);
    short4n o;
    o.x = f2bf(x.x * inv); o.y = f2bf(x.y * inv);
    o.z = f2bf(x.z * inv); o.w = f2bf(x.w * inv);
    *(short4n*)(cf + (size_t)i * D + lane * 4) = o;   // row-major, coalesced
  } else if (bid < 1536) {
    int b = ((bid - 1024) << 2) | (tid >> 6);  // [0, 2048)
    int lane = tid & 63;
    const float* p = preds + (size_t)b * C;
    float m = -1e30f;
    for (int j = lane; j < C; j += 64) m = fmaxf(m, p[j]);
    #pragma unroll
    for (int mk = 32; mk; mk >>= 1) m = fmaxf(m, __shfl_xor(m, mk));
    float s = 0.f;
    for (int j = lane; j < C; j += 64) s += __expf(p[j] - m);
    #pragma unroll
    for (int mk = 32; mk; mk >>= 1) s += __shfl_xor(s, mk);
    int lab = labels[b];
    float nll = p[lab] - (m + logf(s));  // log p_t
    float pt = __expf(nll);
    float md = 1.f - pt;
    md = md * md;  // gamma = 2
    if (lane == 0) modv[b] = md;
  } else {
    __shared__ int h[C];
    for (int t = tid; t < C; t += 256) h[t] = 0;
    __syncthreads();
    for (int t = tid; t < B; t += 256) atomicAdd(&h[labels[t]], 1);
    __syncthreads();
    for (int t = tid; t < C; t += 256) hist[t] = h[t];
    if (tid == 0) out[0] = 0.f;   // finalize atomicAdds onto this
  }
}

// ---------------------------------------------------------------------------
// gemm kernel: SYMMETRIC upper-triangle blocks (528 of 1024). Each
// off-diagonal block (bi,bj) feeds BOTH row-strip bi (row-reduce over l16)
// and row-strip bj (col-reduce: in-register over regs/row-tiles + shuffle
// over quad; valid because exp(s_ij-K) and the label-match condition are
// symmetric in i,j). Diagonal blocks: direct path only, with self-exclusion.
// Partial slots ZP[row][cb] (float2 {z,p}): row in strip r gets direct
// writes at cb=bj (bj>=r) and transposed writes at cb=bi (bi<r) — all 32
// slots written exactly once, no atomics, no init needed.
// LDS staging: m97-style global_load_lds width=16, swizzled chunks
// (c ^ (r&7)) so ds_read_b128 spreads across banks.
// ---------------------------------------------------------------------------
__global__ __launch_bounds__(256) void gemm_kernel(
    const short* __restrict__ cf, const int* __restrict__ labels,
    float2* __restrict__ ZP) {
  __shared__ short smem[2 * 128 * BK];     // A tile | B tile, 16KB each
  short* At = smem;
  short* Bt = smem + 128 * BK;

  // triangular decode: linear block -> (bi, bj), bi <= bj
  int t = blockIdx.x, bi = 0;
  while (t >= NSTRIP - bi) { t -= NSTRIP - bi; ++bi; }
  const int bj = bi + t;
  const bool diag = (bi == bj);

  const int tid = threadIdx.x;
  const int lane = tid & 63;
  const int wave = tid >> 6;
  const int l16 = lane & 15;
  const int quad = lane >> 4;
  const int row0g = bi * 128;
  const int col0g = bj * 128;
  const int rw0 = (wave >> 1) * 64;        // wave's row-quadrant in tile
  const int cw0 = (wave & 1) * 64;         // wave's col-quadrant in tile

  floatx4 acc[4][4] = {};

  for (int it = 0; it < NKI; ++it) {
    const int ko = it * BK;                // K offset (elements)
    if (it) __syncthreads();               // prev iter's reads done
    #pragma unroll
    for (int n = 0; n < 4; ++n) {
      int s = n * 256 + tid;               // LDS 16B-slot index [0,1024)
      int r = s >> 3;                      // tile row 0..127
      int c = (s & 7) ^ (r & 7);           // swizzled source chunk
      gload_lds16(cf + (size_t)(row0g + r) * D + ko + c * 8, At + s * 8);
      gload_lds16(cf + (size_t)(col0g + r) * D + ko + c * 8, Bt + s * 8);
    }
    asm volatile("s_waitcnt vmcnt(0)" ::: "memory");
    __syncthreads();
    #pragma unroll
    for (int ks8 = 0; ks8 < 8; ks8 += 4) { // chunk base: 0 (k=0..31), 4 (k=32..63)
      bf16x8 a[4], b[4];
      #pragma unroll
      for (int tt = 0; tt < 4; ++tt) {
        int ra = rw0 + tt * 16 + l16;
        int ca = (ks8 + quad) ^ (ra & 7);
        a[tt] = *(const bf16x8*)(At + (ra * 8 + ca) * 8);
        int rb = cw0 + tt * 16 + l16;
        int cb = (ks8 + quad) ^ (rb & 7);
        b[tt] = *(const bf16x8*)(Bt + (rb * 8 + cb) * 8);
      }
      #pragma unroll
      for (int rt = 0; rt < 4; ++rt)
        #pragma unroll
        for (int ct = 0; ct < 4; ++ct)
          acc[rt][ct] = __builtin_amdgcn_mfma_f32_16x16x32_bf16(a[rt], b[ct], acc[rt][ct], 0, 0, 0);
    }
  }

  // ---- epilogue. C/D layout: col = lane&15, row = quad*4 + reg ----
  const float invT = 1.0f / TEMP;
  int clab[4], colg[4];
  #pragma unroll
  for (int ct = 0; ct < 4; ++ct) {
    colg[ct] = col0g + cw0 + ct * 16 + l16;
    clab[ct] = labels[colg[ct] & (B - 1)];
  }
  float zr[4][4], pr[4][4];                   // row sums [rt][e]
  float zc[4] = {0.f, 0.f, 0.f, 0.f};         // col sums [ct]
  float pc[4] = {0.f, 0.f, 0.f, 0.f};
  #pragma unroll
  for (int rt = 0; rt < 4; ++rt) {
    #pragma unroll
    for (int e = 0; e < 4; ++e) {
      int row = row0g + rw0 + rt * 16 + quad * 4 + e;
      int rlab = labels[row & (B - 1)];
      float z4 = 0.f, p4 = 0.f;
      #pragma unroll
      for (int ct = 0; ct < 4; ++ct) {
        float sv = acc[rt][ct][e] * invT;
        float z = __expf(sv - invT);
        float p = (clab[ct] == rlab) ? sv : 0.f;
        if (diag && colg[ct] == row) { z = 0.f; p = 0.f; }  // self-exclusion
        z4 += z; p4 += p;
        zc[ct] += z; pc[ct] += p;
      }
      #pragma unroll
      for (int mk = 1; mk < 16; mk <<= 1) {   // reduce across l16 (cols)
        z4 += __shfl_xor(z4, mk);
        p4 += __shfl_xor(p4, mk);
      }
      zr[rt][e] = z4; pr[rt][e] = p4;
    }
  }
  #pragma unroll
  for (int ct = 0; ct < 4; ++ct) {            // reduce across quad (rows)
    #pragma unroll
    for (int mk = 16; mk < 64; mk <<= 1) {
      zc[ct] += __shfl_xor(zc[ct], mk);
      pc[ct] += __shfl_xor(pc[ct], mk);
    }
  }

  // cross-wave combine via LDS (reuse tile smem), then one store per slot
  __syncthreads();
  float* Zl = (float*)smem;    // [128] row partials from col-half-1 waves
  float* Pl = Zl + 128;
  float* Zc = Pl + 128;        // [128] col partials from row-half-1 waves
  float* Pc = Zc + 128;
  if ((wave & 1) && l16 == 0) {
    #pragma unroll
    for (int rt = 0; rt < 4; ++rt)
      #pragma unroll
      for (int e = 0; e < 4; ++e) {
        int rloc = rw0 + rt * 16 + quad * 4 + e;
        Zl[rloc] = zr[rt][e]; Pl[rloc] = pr[rt][e];
      }
  }
  if (!diag && (wave >> 1) && quad == 0) {
    #pragma unroll
    for (int ct = 0; ct < 4; ++ct) {
      int cloc = cw0 + ct * 16 + l16;
      Zc[cloc] = zc[ct]; Pc[cloc] = pc[ct];
    }
  }
  __syncthreads();
  if (!(wave & 1) && l16 == 0) {
    #pragma unroll
    for (int rt = 0; rt < 4; ++rt)
      #pragma unroll
      for (int e = 0; e < 4; ++e) {
        int rloc = rw0 + rt * 16 + quad * 4 + e;
        int grow = row0g + rloc;
        ZP[(size_t)grow * NSTRIP + bj] =
            make_float2(zr[rt][e] + Zl[rloc], pr[rt][e] + Pl[rloc]);
      }
  }
  if (!diag && !(wave >> 1) && quad == 0) {
    #pragma unroll
    for (int ct = 0; ct < 4; ++ct) {
      int cloc = cw0 + ct * 16 + l16;
      int gcol = col0g + cloc;
      ZP[(size_t)gcol * NSTRIP + bi] =
          make_float2(zc[ct] + Zc[cloc], pc[ct] + Pc[cloc]);
    }
  }
}

// ---------------------------------------------------------------------------
// finalize: one row per thread (contiguous 256B of partials), 16 blocks;
// atomicAdd block partials onto out[0] (zeroed by prep).
// ---------------------------------------------------------------------------
__global__ __launch_bounds__(256) void finalize_kernel(
    const float2* __restrict__ ZP, const float* __restrict__ modv,
    const int* __restrict__ hist, const int* __restrict__ labels,
    float* __restrict__ out) {
  __shared__ float red[4];
  const int i = blockIdx.x * 256 + threadIdx.x;   // row [0, 4096)
  const float4* zp4 = (const float4*)(ZP + (size_t)i * NSTRIP);  // 16 x float4
  float Zi = 0.f, Pi = 0.f;
  #pragma unroll
  for (int q = 0; q < 16; ++q) {
    float4 v = zp4[q];        // {z,p,z,p}
    Zi += v.x + v.z;
    Pi += v.y + v.w;
  }
  int b = i & (B - 1);
  float c = 2.f * (float)hist[labels[b]] - 1.f;   // positives excl. self
  float lse = (1.0f / TEMP) + logf(Zi);
  float accv = modv[b] * (Pi - c * lse) / c;
  #pragma unroll
  for (int m = 32; m; m >>= 1) accv += __shfl_xor(accv, m);
  if ((threadIdx.x & 63) == 0) red[threadIdx.x >> 6] = accv;
  __syncthreads();
  if (threadIdx.x == 0)
    atomicAdd(out, -(red[0] + red[1] + red[2] + red[3]) / (float)N);
}

extern "C" void kernel_launch(void* const* d_in, const int* in_sizes, int n_in,
                              void* d_out, int out_size, void* d_ws, size_t ws_size,
                              hipStream_t stream) {
  const float* feat = (const float*)d_in[0];   // [B, V, D] fp32
  const float* preds = (const float*)d_in[1];  // [B, C] fp32
  const int* labels = (const int*)d_in[2];     // [B] int32
  float* out = (float*)d_out;

  char* ws = (char*)d_ws;
  float*  modv = (float*)(ws);                   // 8 KB
  int*    hist = (int*)  (ws + 8192);            // ~4 KB
  float2* ZP   = (float2*)(ws + 16384);          // [4096][32] float2 = 1 MB
  short*  cf   = (short*)(ws + 16384 + 1048576); // [4096][256] bf16 = 2 MB

  prep_kernel<<<1537, 256, 0, stream>>>(feat, preds, labels, cf, modv, hist, out);
  gemm_kernel<<<NBLK, 256, 0, stream>>>(cf, labels, ZP);
  finalize_kernel<<<16, 256, 0, stream>>>(ZP, modv, hist, labels, out);
}